// Round 2
// baseline (90.742 us; speedup 1.0000x reference)
//
#include <hip/hip_runtime.h>

// Quantizer_189: 1-D VQ codebook lookup. x: [16,1,512,512] fp32 (N=4,194,304
// scalars; C=D=1 so transposes are no-ops), weight: [128,1].
//
// Reference model (NumPy fp32, per-op rounding, NO fma — verified, absmax 0.0):
//   dist_k = fl( fl( fl(x*x) + fl(w_k*w_k) ) - fl( fl(2x) * w_k ) )
//   idx    = np.argmin(dist) — first ORIGINAL index wins ties
//   out    = w[idx]
//
// Round-6 redesign (dependent-LDS-chain removal — round-5 bank-conflict fix
// was neutral, so the limiter is per-element serial LDS latency, not banks):
//   Old: per element, 4-level LDS binary search (4 DEPENDENT ds_reads ~120cy
//        each) + candidate gathers = 5 serial LDS stages, ~135 VALU.
//   New: per block, build a 1024-bucket LUT over x's value range storing a
//        candidate window (start,end). Per element: bucketize (4 VALU) ->
//        1 LUT read -> 8 parallel candidate reads = 2 serial LDS stages,
//        ~95 VALU, 9 volatile-asm barriers (was 17).
//
// Window correctness (rigorous, not heuristic): with |x|<=5.5, |w|<=3.5 the
// fp32 distance errs by eta <= 5 half-ulps@|d|<=81 ~= 1.9e-5, so any codeword
// that can win satisfies |x-w| <= |x-w*| + sqrt(2*eta) <= |x-w*| + 6.3e-3.
// For x in [L,R] with outside brackets wa<=L, wb>=R this implies winners'
// VALUES lie in [wa - delta, wb + delta]. We build with delta = 1.25e-2 (2x
// margin) and L,R padded +-1.5 buckets (absorbs query-side fp rounding of the
// bucket map). The evaluated set is a SUPERSET of all global minima; extra
// candidates are harmless (d >= d_min; exact ties resolved by the si[] fixup,
// which matches np.argmin's first-original-index rule exactly).
//
// CRITICAL (round 1/2 lesson): device default -ffp-contract fuses mul into
// add/sub -> fma, breaking bit-exactness. Keep pragma + opaque asm barriers
// on every product (x*x, w*w, 2x*w).

constexpr int K     = 128;
constexpr int NB    = 1024;   // LUT buckets
constexpr int EPT   = 8;
constexpr int BLOCK = 256;

#define DELTA 0.0125f

__global__ __launch_bounds__(BLOCK) void vq_kernel(const float* __restrict__ x,
                                                   const float* __restrict__ w,
                                                   float* __restrict__ out,
                                                   long n, int kk) {
#pragma clang fp contract(off)
    __shared__ float wraw[K];
    __shared__ float svw[2 * K];  // [0,K): sorted values asc; [K,2K): fl(w*w)
    __shared__ int   si[K];       // original index per sorted pos
    __shared__ int   lut[NB];     // packed: start | (end << 8)

    const int t = threadIdx.x;
    if (t < K) {
        wraw[t]    = (t < kk) ? w[t] : __builtin_inff();
        svw[t]     = __builtin_inff();   // pad slots (d -> inf/NaN, never win)
        svw[K + t] = __builtin_inff();
        si[t]      = 0x7fffffff;
    }
    __syncthreads();
    if (t < kk) {
        // Stable O(K) rank sort: rank = #{strictly less} + #{equal, earlier}.
        float v = wraw[t];
        int rank = 0;
        for (int j = 0; j < kk; ++j) {
            float u = wraw[j];
            rank += (u < v) || (u == v && j < t);
        }
        float v2 = v * v;                 // fl(w*w)
        asm volatile("" : "+v"(v2));      // keep standalone product
        svw[rank]     = v;
        svw[K + rank] = v2;
        si[rank]      = t;
    }
    __syncthreads();

    const float lo    = svw[0];
    const float hi    = svw[kk - 1];
    const float range = hi - lo;
    const float scale = (range > 0.f) ? (float)NB / range : 0.f;
    const float binv  = (range > 0.f) ? range / (float)NB : 0.f;
    const int   sMax  = (kk > 8 ? kk : 8) - 8;

    // ---- LUT build: 4 buckets/thread. Two 7-step ladders (exact lower_bound
    // with a final correction) + short linear walks for the delta halo.
    for (int b = t; b < NB; b += BLOCK) {
        float L = lo + ((float)b - 1.5f) * binv;   // padded bucket edges
        float R = lo + ((float)b + 2.5f) * binv;
        int pL = 0;
#pragma unroll
        for (int st = 64; st > 0; st >>= 1)
            if (svw[pL + st - 1] < L) pL += st;
        if (svw[pL] < L) ++pL;                      // exact #{sv < L}
        int pR = 0;
#pragma unroll
        for (int st = 64; st > 0; st >>= 1)
            if (svw[pR + st - 1] < R) pR += st;
        if (svw[pR] < R) ++pR;                      // exact #{sv < R}

        float wa  = svw[pL > 0 ? pL - 1 : 0];       // bracket below (finite)
        float wb  = svw[pR < kk ? pR : kk - 1];     // bracket above (finite)
        float tlo = wa - DELTA;
        float thi = wb + DELTA;

        int s0 = pL > 0 ? pL - 1 : 0;               // walk down to #{sv < tlo}
        while (s0 > 0 && svw[s0 - 1] >= tlo) --s0;
        int e0 = pR;                                // walk up to #{sv <= thi}
        while (e0 < kk && svw[e0] <= thi) ++e0;

        if (s0 > sMax) s0 = sMax;                   // 8-wide read stays in [0,K)
        lut[b] = s0 | (e0 << 8);
    }
    __syncthreads();

    long base = ((long)blockIdx.x * BLOCK + t) * (long)EPT;
    if (base + EPT <= n) {
        float4 a  = *(const float4*)(x + base);
        float4 b4 = *(const float4*)(x + base + 4);
        float xs[EPT] = {a.x, a.y, a.z, a.w, b4.x, b4.y, b4.z, b4.w};
        float res[EPT];
#pragma unroll
        for (int e = 0; e < EPT; ++e) {
            float xv = xs[e];
            float x2 = xv * xv;            // fl(x*x)
            asm volatile("" : "+v"(x2));   // block fma(x,x,w2)
            float tx = xv + xv;            // fl(2x), exact

            // Bucketize (any fp rounding here is absorbed by build padding).
            float fi = (xv - lo) * scale;
            int idx = (int)fi;
            idx = idx < 0 ? 0 : (idx > NB - 1 ? NB - 1 : idx);
            int pk = lut[idx];
            int s  = pk & 0xff;
            int en = pk >> 8;

            float best = __builtin_inff();
            float bw   = 0.0f;
            unsigned tie = 0u;
#pragma unroll
            for (int c = 0; c < 8; ++c) {
                float wv = svw[s + c];
                float w2 = svw[K + s + c];      // fl(w*w), precomputed
                float sum  = x2 + w2;           // fl(x^2 + w^2)
                float prod = tx * wv;           // fl(2x * w)
                asm volatile("" : "+v"(prod));  // block fma fusion into sub
                float d = sum - prod;           // fl(sum - prod)
                bool lt = d < best;
                tie |= (d == best) ? 1u : 0u;
                best = lt ? d : best;
                bw   = lt ? wv : bw;
            }
            // Rare: window wider than 8 (packed codewords) — finish it.
            if (__builtin_expect(en > s + 8, 0)) {
                for (int j = s + 8; j < en; ++j) {
                    float wv = svw[j];
                    float w2 = svw[K + j];
                    float sum  = x2 + w2;
                    float prod = tx * wv;
                    asm volatile("" : "+v"(prod));
                    float d = sum - prod;
                    bool lt = d < best;
                    tie |= (d == best) ? 1u : 0u;
                    best = lt ? d : best;
                    bw   = lt ? wv : bw;
                }
            }
            res[e] = bw;
            // Rare exact-tie fixup: np.argmin keeps smallest ORIGINAL index.
            if (__builtin_expect(tie != 0u, 0)) {
                int hiEnd = en > s + 8 ? en : s + 8;
                float bb = __builtin_inff(), bwv = 0.0f;
                int bi = 0x7fffffff;
                for (int j = s; j < hiEnd; ++j) {
                    float wv = svw[j];
                    float w2 = svw[K + j];
                    float sum  = x2 + w2;
                    float prod = tx * wv;
                    asm volatile("" : "+v"(prod));
                    float d = sum - prod;
                    int oi = si[j];
                    if (d < bb || (d == bb && oi < bi)) { bb = d; bi = oi; bwv = wv; }
                }
                res[e] = bwv;
            }
        }
        *(float4*)(out + base)     = make_float4(res[0], res[1], res[2], res[3]);
        *(float4*)(out + base + 4) = make_float4(res[4], res[5], res[6], res[7]);
    } else {
        // Tail (not hit for N=4,194,304): exact brute force over kk entries.
        for (long i = base; i < n; ++i) {
            float xv = x[i];
            float x2 = xv * xv;
            asm volatile("" : "+v"(x2));
            float tx = xv + xv;
            float bb = __builtin_inff(), bwv = 0.0f;
            int bi = 0x7fffffff;
            for (int p0 = 0; p0 < kk; ++p0) {
                float wv = svw[p0];
                float w2 = svw[K + p0];
                float sum  = x2 + w2;
                float prod = tx * wv;
                asm volatile("" : "+v"(prod));
                float d = sum - prod;
                int oi = si[p0];
                if (d < bb || (d == bb && oi < bi)) { bb = d; bi = oi; bwv = wv; }
            }
            out[i] = bwv;
        }
    }
}

extern "C" void kernel_launch(void* const* d_in, const int* in_sizes, int n_in,
                              void* d_out, int out_size, void* d_ws, size_t ws_size,
                              hipStream_t stream) {
    const float* x = (const float*)d_in[0];
    const float* w = (const float*)d_in[1];
    float* out     = (float*)d_out;
    long n = (long)in_sizes[0];
    int  kk = in_sizes[1] < K ? in_sizes[1] : K;

    long threads_needed = (n + EPT - 1) / EPT;
    long grid = (threads_needed + BLOCK - 1) / BLOCK;
    vq_kernel<<<(int)grid, BLOCK, 0, stream>>>(x, w, out, n, kk);
}

// Round 3
// 89.991 us; speedup vs baseline: 1.0083x; 1.0083x over previous
//
#include <hip/hip_runtime.h>

// Quantizer_189: 1-D VQ codebook lookup. x: [16,1,512,512] fp32 (N=4,194,304
// scalars; C=D=1 so transposes are no-ops), weight: [128,1].
//
// Reference model (NumPy fp32, per-op rounding, NO fma — verified, absmax 0.0):
//   dist_k = fl( fl( fl(x*x) + fl(w_k*w_k) ) - fl( fl(2x) * w_k ) )
//   idx    = np.argmin(dist) — first ORIGINAL index wins ties
//   out    = w[idx]
//
// Round-7 split (amortize per-block work — rounds 0-2 showed the kernel pinned
// at ~30-40 us regardless of per-element body; the shared cost is per-block
// redundant sort/build, so move it to a one-block prologue kernel):
//   Kernel A (1 block): rank-sort codebook, build 1024-bucket window LUT,
//     write {sv[128], si[128], lut[1024], lo, scale} (~5.6 KB) to d_ws.
//   Kernel B (2048 blocks): copy ws->LDS (coalesced, ~6 instrs/thread, ONE
//     barrier — no sort, no ladders), then stream: per element bucketize ->
//     1 LUT read -> 8 parallel b32 candidate reads -> exact fp32 distances.
//     w^2 recomputed with a contract-off mul (bit-identical; halves LDS
//     traffic vs paired (w,w^2) reads).
//   Cross-kernel ws visibility: same-stream dispatch ordering (kernel-boundary
//   cache writeback/invalidate) — standard HIP guarantee.
//
// Window correctness (rigorous): with |x|<=5.5, |w|<=3.5 the fp32 distance
// errs by eta <= ~9e-6, so any codeword that can win the computed argmin
// satisfies |x-w| <= |x-w*| + sqrt(2*eta) <= |x-w*| + 6.3e-3. For x in [L,R]
// with outside brackets wa<=L, wb>=R, winners' VALUES lie in [wa-d, wb+d].
// Build uses DELTA=1.25e-2 (2x margin) and L,R padded +-1.5 buckets (absorbs
// query-side fp rounding of the bucket map). Evaluated set = [s0, max(s0+8,e0))
// is a SUPERSET of all global minima; extra candidates are harmless (exact
// ties resolved by the si[] fixup, matching np.argmin's first-index rule).
//
// CRITICAL (round 1/2 lesson): device default -ffp-contract fuses mul into
// add/sub -> fma, breaking bit-exactness. Keep pragma + opaque asm barriers
// on every product (x*x, w*w, 2x*w).

constexpr int K     = 128;
constexpr int NB    = 1024;   // LUT buckets
constexpr int EPT   = 8;
constexpr int BLOCK = 256;

// d_ws layout (float/int indices; floats and ints are both 4 B):
constexpr int SV_OFF  = 0;            // float sv[128], sorted ascending
constexpr int SI_OFF  = K;            // int   si[128], original index per rank
constexpr int LUT_OFF = 2 * K;        // int   lut[1024], s0 | (e0 << 8)
constexpr int HDR_OFF = 2 * K + NB;   // float lo, float scale

#define DELTA 0.0125f

// ---------------- Kernel A: one-block prologue (sort + LUT build) ----------
__global__ __launch_bounds__(BLOCK) void vq_build(const float* __restrict__ w,
                                                  float* __restrict__ ws,
                                                  int kk) {
#pragma clang fp contract(off)
    __shared__ float wraw[K];
    __shared__ float sv[K];
    __shared__ int   sidx[K];
    const int t = threadIdx.x;
    if (t < K) {
        wraw[t] = (t < kk) ? w[t] : __builtin_inff();
        sv[t]   = __builtin_inff();                  // pad slots
        sidx[t] = 0x7fffffff;
    }
    __syncthreads();
    if (t < kk) {
        // Stable O(K) rank sort: rank = #{strictly less} + #{equal, earlier}.
        float v = wraw[t];
        int rank = 0;
        for (int j = 0; j < kk; ++j) {
            float u = wraw[j];
            rank += (u < v) || (u == v && j < t);
        }
        sv[rank]   = v;
        sidx[rank] = t;
    }
    __syncthreads();

    const float lo    = sv[0];
    const float hi    = sv[kk - 1];
    const float range = hi - lo;
    const float scale = (range > 0.f) ? (float)NB / range : 0.f;
    const float binv  = (range > 0.f) ? range / (float)NB : 0.f;
    const int   sMax  = (kk > 8 ? kk : 8) - 8;

    if (t < K) {
        ws[SV_OFF + t] = sv[t];
        ((int*)ws)[SI_OFF + t] = sidx[t];
    }
    if (t == 0) {
        ws[HDR_OFF]     = lo;
        ws[HDR_OFF + 1] = scale;
    }

    // 4 consecutive buckets per thread: ladder once for the first, then
    // incremental forward walks (bucket edges are monotone in b).
    const int b0 = t * 4;                         // 256 threads x 4 = 1024
    float L0 = lo + ((float)b0 - 1.5f) * binv;    // padded bucket edges
    float R0 = lo + ((float)b0 + 2.5f) * binv;
    int pL = 0, pR = 0;
#pragma unroll
    for (int st = 64; st > 0; st >>= 1)
        if (sv[pL + st - 1] < L0) pL += st;
    if (pL < K && sv[pL] < L0) ++pL;              // exact #{sv < L0}
#pragma unroll
    for (int st = 64; st > 0; st >>= 1)
        if (sv[pR + st - 1] < R0) pR += st;
    if (pR < K && sv[pR] < R0) ++pR;              // exact #{sv < R0}

    for (int j = 0; j < 4; ++j) {
        int b = b0 + j;
        float Lb = lo + ((float)b - 1.5f) * binv;
        float Rb = lo + ((float)b + 2.5f) * binv;
        while (pL < kk && sv[pL] < Lb) ++pL;      // exact #{sv < Lb}
        while (pR < kk && sv[pR] < Rb) ++pR;      // exact #{sv < Rb}

        float wa  = sv[pL > 0 ? pL - 1 : 0];      // bracket below (finite)
        float wb  = sv[pR < kk ? pR : kk - 1];    // bracket above (finite)
        float tlo = wa - DELTA;
        float thi = wb + DELTA;

        int s0 = pL > 0 ? pL - 1 : 0;             // walk down: #{sv < tlo}
        while (s0 > 0 && sv[s0 - 1] >= tlo) --s0;
        int e0 = pR;                              // walk up: #{sv <= thi}
        while (e0 < kk && sv[e0] <= thi) ++e0;

        if (s0 > sMax) s0 = sMax;                 // 8-wide read stays in [0,K)
        ((int*)ws)[LUT_OFF + b] = s0 | (e0 << 8);
    }
}

// ---------------- Kernel B: streaming quantize ----------------------------
__global__ __launch_bounds__(BLOCK) void vq_main(const float* __restrict__ x,
                                                 const float* __restrict__ ws,
                                                 float* __restrict__ out,
                                                 long n, int kk) {
#pragma clang fp contract(off)
    __shared__ float sv[K];
    __shared__ int   si[K];
    __shared__ alignas(16) int lut[NB];

    const int t = threadIdx.x;
    if (t < K) {
        sv[t] = ws[SV_OFF + t];
        si[t] = ((const int*)ws)[SI_OFF + t];
    }
    {   // 4 KB LUT: one int4 per thread, coalesced.
        int4 lv = ((const int4*)(ws + LUT_OFF))[t];
        *(int4*)&lut[4 * t] = lv;
    }
    const float lo    = ws[HDR_OFF];        // same line for all lanes: broadcast
    const float scale = ws[HDR_OFF + 1];
    __syncthreads();

    long base = ((long)blockIdx.x * BLOCK + t) * (long)EPT;
    if (base + EPT <= n) {
        float4 a  = *(const float4*)(x + base);
        float4 b4 = *(const float4*)(x + base + 4);
        float xs[EPT] = {a.x, a.y, a.z, a.w, b4.x, b4.y, b4.z, b4.w};
        float res[EPT];
#pragma unroll
        for (int e = 0; e < EPT; ++e) {
            float xv = xs[e];
            float x2 = xv * xv;            // fl(x*x)
            asm volatile("" : "+v"(x2));   // block fma(x,x,w2)
            float tx = xv + xv;            // fl(2x), exact

            // Bucketize (fp rounding here is absorbed by build-side padding).
            float fi = (xv - lo) * scale;
            int idx = (int)fi;
            idx = idx < 0 ? 0 : (idx > NB - 1 ? NB - 1 : idx);
            int pk = lut[idx];
            int s  = pk & 0xff;
            int en = pk >> 8;

            float best = __builtin_inff();
            float bw   = 0.0f;
            unsigned tie = 0u;
#pragma unroll
            for (int c = 0; c < 8; ++c) {
                float wv = sv[s + c];
                float w2 = wv * wv;             // fl(w*w)
                asm volatile("" : "+v"(w2));    // keep standalone product
                float sum  = x2 + w2;           // fl(x^2 + w^2)
                float prod = tx * wv;           // fl(2x * w)
                asm volatile("" : "+v"(prod));  // block fma fusion into sub
                float d = sum - prod;           // fl(sum - prod)
                bool lt = d < best;
                tie |= (d == best) ? 1u : 0u;
                best = lt ? d : best;
                bw   = lt ? wv : bw;
            }
            // Rare: window wider than 8 (clustered codewords) — finish it.
            if (__builtin_expect(en > s + 8, 0)) {
                for (int j = s + 8; j < en; ++j) {
                    float wv = sv[j];
                    float w2 = wv * wv;
                    asm volatile("" : "+v"(w2));
                    float sum  = x2 + w2;
                    float prod = tx * wv;
                    asm volatile("" : "+v"(prod));
                    float d = sum - prod;
                    bool lt = d < best;
                    tie |= (d == best) ? 1u : 0u;
                    best = lt ? d : best;
                    bw   = lt ? wv : bw;
                }
            }
            res[e] = bw;
            // Rare exact-tie fixup: np.argmin keeps smallest ORIGINAL index.
            if (__builtin_expect(tie != 0u, 0)) {
                int hiEnd = en > s + 8 ? en : s + 8;
                float bb = __builtin_inff(), bwv = 0.0f;
                int bi = 0x7fffffff;
                for (int j = s; j < hiEnd; ++j) {
                    float wv = sv[j];
                    float w2 = wv * wv;
                    asm volatile("" : "+v"(w2));
                    float sum  = x2 + w2;
                    float prod = tx * wv;
                    asm volatile("" : "+v"(prod));
                    float d = sum - prod;
                    int oi = si[j];
                    if (d < bb || (d == bb && oi < bi)) { bb = d; bi = oi; bwv = wv; }
                }
                res[e] = bwv;
            }
        }
        *(float4*)(out + base)     = make_float4(res[0], res[1], res[2], res[3]);
        *(float4*)(out + base + 4) = make_float4(res[4], res[5], res[6], res[7]);
    } else {
        // Tail (not hit for N=4,194,304): exact brute force over kk entries.
        for (long i = base; i < n; ++i) {
            float xv = x[i];
            float x2 = xv * xv;
            asm volatile("" : "+v"(x2));
            float tx = xv + xv;
            float bb = __builtin_inff(), bwv = 0.0f;
            int bi = 0x7fffffff;
            for (int p0 = 0; p0 < kk; ++p0) {
                float wv = sv[p0];
                float w2 = wv * wv;
                asm volatile("" : "+v"(w2));
                float sum  = x2 + w2;
                float prod = tx * wv;
                asm volatile("" : "+v"(prod));
                float d = sum - prod;
                int oi = si[p0];
                if (d < bb || (d == bb && oi < bi)) { bb = d; bi = oi; bwv = wv; }
            }
            out[i] = bwv;
        }
    }
}

extern "C" void kernel_launch(void* const* d_in, const int* in_sizes, int n_in,
                              void* d_out, int out_size, void* d_ws, size_t ws_size,
                              hipStream_t stream) {
    const float* x = (const float*)d_in[0];
    const float* w = (const float*)d_in[1];
    float* out     = (float*)d_out;
    float* ws      = (float*)d_ws;
    long n = (long)in_sizes[0];
    int  kk = in_sizes[1] < K ? in_sizes[1] : K;

    vq_build<<<1, BLOCK, 0, stream>>>(w, ws, kk);

    long threads_needed = (n + EPT - 1) / EPT;
    long grid = (threads_needed + BLOCK - 1) / BLOCK;
    vq_main<<<(int)grid, BLOCK, 0, stream>>>(x, ws, out, n, kk);
}